// Round 1
// baseline (595.901 us; speedup 1.0000x reference)
//
#include <hip/hip_runtime.h>

#define NE 640000
#define NN 20000

typedef __attribute__((ext_vector_type(8))) short s16x8;
typedef __attribute__((ext_vector_type(4))) short s16x4;
typedef __attribute__((ext_vector_type(4))) float f32x4;

// LDS strides in bf16 elements (K padded +8 to spread banks)
#define SW1 200   // W1^T [128][192+8]
#define SW2 136   // W2^T [64][128+8]
#define SEI 200   // Ein  [64][192+8]
#define SEH 136   // Eh   [64][128+8]

__device__ __forceinline__ short f2bf(float f) {
  unsigned int u = __float_as_uint(f);
  u += 0x7fffu + ((u >> 16) & 1u);   // RNE
  return (short)(u >> 16);
}

// load 16 fp32, convert, store 32B to LDS (16B-aligned dst)
__device__ __forceinline__ void stage16(short* dst, const float* src) {
  const f32x4* s4 = (const f32x4*)src;
  f32x4 v0 = s4[0], v1 = s4[1], v2 = s4[2], v3 = s4[3];
  s16x8 lo, hi;
  lo[0]=f2bf(v0[0]); lo[1]=f2bf(v0[1]); lo[2]=f2bf(v0[2]); lo[3]=f2bf(v0[3]);
  lo[4]=f2bf(v1[0]); lo[5]=f2bf(v1[1]); lo[6]=f2bf(v1[2]); lo[7]=f2bf(v1[3]);
  hi[0]=f2bf(v2[0]); hi[1]=f2bf(v2[1]); hi[2]=f2bf(v2[2]); hi[3]=f2bf(v2[3]);
  hi[4]=f2bf(v3[0]); hi[5]=f2bf(v3[1]); hi[6]=f2bf(v3[2]); hi[7]=f2bf(v3[3]);
  ((s16x8*)dst)[0] = lo;
  ((s16x8*)dst)[1] = hi;
}

// W1 [192][128] -> sW1[h][k] (transposed, bf16); W2 [128][64] -> sW2[d][k]
__device__ __forceinline__ void stage_weights(const float* W1, const float* W2,
                                              short* sW1, short* sW2, int t) {
  #pragma unroll
  for (int i = 0; i < 24; ++i) {
    int idx4 = t + i * 256;                 // 6144 float4
    int k = idx4 >> 5;                      // row of W1 (k-dim)
    int n0 = (idx4 & 31) << 2;              // col (h-dim)
    f32x4 v = ((const f32x4*)W1)[idx4];
    sW1[(n0+0)*SW1 + k] = f2bf(v[0]);
    sW1[(n0+1)*SW1 + k] = f2bf(v[1]);
    sW1[(n0+2)*SW1 + k] = f2bf(v[2]);
    sW1[(n0+3)*SW1 + k] = f2bf(v[3]);
  }
  #pragma unroll
  for (int i = 0; i < 8; ++i) {
    int idx4 = t + i * 256;                 // 2048 float4
    int k = idx4 >> 4;
    int n0 = (idx4 & 15) << 2;
    f32x4 v = ((const f32x4*)W2)[idx4];
    sW2[(n0+0)*SW2 + k] = f2bf(v[0]);
    sW2[(n0+1)*SW2 + k] = f2bf(v[1]);
    sW2[(n0+2)*SW2 + k] = f2bf(v[2]);
    sW2[(n0+3)*SW2 + k] = f2bf(v[3]);
  }
}

// Edge model: for 64-edge tiles, e_h = relu([x_s|x_d|ea] @ W1 + b1), out = e_h @ W2 + b2.
// Computed transposed (D' = W^T * Ein^T) so weights are the A-operand and live in
// registers; each wave owns 16 edges (its own LDS rows) -> no in-loop barriers.
__global__ __launch_bounds__(256, 1)
void edge_kernel(const float* __restrict__ x, const int* __restrict__ eidx,
                 const float* __restrict__ ea,
                 const float* __restrict__ We1, const float* __restrict__ be1,
                 const float* __restrict__ We2, const float* __restrict__ be2,
                 float* __restrict__ edge_out, float* __restrict__ agg)
{
  __shared__ short sW1[128 * SW1];
  __shared__ short sW2[64 * SW2];
  __shared__ short sEin[64 * SEI];
  __shared__ short sEh[64 * SEH];
  __shared__ int sDest[64];

  const int t = threadIdx.x;
  const int lane = t & 63;
  const int w = t >> 6;          // wave 0..3
  const int r = lane & 15;
  const int g = lane >> 4;

  stage_weights(We1, We2, sW1, sW2, t);
  __syncthreads();

  // weight fragments in registers: A-operand = W^T tile rows (h / d dims)
  s16x8 w1f[8][6];
  #pragma unroll
  for (int n = 0; n < 8; ++n) {
    #pragma unroll
    for (int kk = 0; kk < 6; ++kk)
      w1f[n][kk] = *(const s16x8*)&sW1[(n*16 + r) * SW1 + kk*32 + g*8];
  }
  s16x8 w2f[4][4];
  #pragma unroll
  for (int n = 0; n < 4; ++n) {
    #pragma unroll
    for (int kk = 0; kk < 4; ++kk)
      w2f[n][kk] = *(const s16x8*)&sW2[(n*16 + r) * SW2 + kk*32 + g*8];
  }
  f32x4 b1r[8], b2r[4];
  #pragma unroll
  for (int n = 0; n < 8; ++n) b1r[n] = *(const f32x4*)(be1 + n*16 + g*4);
  #pragma unroll
  for (int n = 0; n < 4; ++n) b2r[n] = *(const f32x4*)(be2 + n*16 + g*4);

  // per-thread constant LDS addresses
  const int el = t >> 2;         // edge slot 0..63 (wave-private range)
  const int p  = t & 3;          // 16-col chunk
  short* stg = &sEin[el*SEI + p*16];
  const short* erow = &sEin[(w*16 + r) * SEI + g*8];
  const short* hrow = &sEh[(w*16 + r) * SEH + g*8];

  const f32x4 zero = {0.f, 0.f, 0.f, 0.f};

  for (int tile = blockIdx.x; tile < NE/64; tile += (int)gridDim.x) {
    const int ebase = tile << 6;
    {
      const int e = ebase + el;
      const int s = eidx[e];
      const int d = eidx[NE + e];
      if (p == 0) sDest[el] = d;
      stage16(stg,       x  + (size_t)s*64 + p*16);
      stage16(stg + 64,  x  + (size_t)d*64 + p*16);
      stage16(stg + 128, ea + (size_t)e*64 + p*16);
    }

    // layer 1: acc1[h-tile] = W1^T * Ein^T   (lane: col=edge r, rows=h g*4+q)
    f32x4 acc1[8];
    #pragma unroll
    for (int n = 0; n < 8; ++n) acc1[n] = zero;
    #pragma unroll
    for (int kk = 0; kk < 6; ++kk) {
      s16x8 ef = *(const s16x8*)(erow + kk*32);
      #pragma unroll
      for (int n = 0; n < 8; ++n)
        acc1[n] = __builtin_amdgcn_mfma_f32_16x16x32_bf16(w1f[n][kk], ef, acc1[n], 0, 0, 0);
    }
    // bias + relu + packed bf16 row write (4 contiguous h per lane)
    #pragma unroll
    for (int n = 0; n < 8; ++n) {
      s16x4 pk;
      #pragma unroll
      for (int q = 0; q < 4; ++q) {
        float v = acc1[n][q] + b1r[n][q];
        pk[q] = f2bf(v > 0.f ? v : 0.f);
      }
      *(s16x4*)&sEh[(w*16 + r) * SEH + n*16 + g*4] = pk;
    }

    // layer 2: acc2[d-tile] = W2^T * Eh^T
    f32x4 acc2[4];
    #pragma unroll
    for (int n = 0; n < 4; ++n) acc2[n] = zero;
    #pragma unroll
    for (int kk = 0; kk < 4; ++kk) {
      s16x8 hf = *(const s16x8*)(hrow + kk*32);
      #pragma unroll
      for (int n = 0; n < 4; ++n)
        acc2[n] = __builtin_amdgcn_mfma_f32_16x16x32_bf16(w2f[n][kk], hf, acc2[n], 0, 0, 0);
    }
    const int eg = ebase + w*16 + r;
    const int dst = sDest[w*16 + r];
    #pragma unroll
    for (int n = 0; n < 4; ++n) {
      f32x4 v = acc2[n] + b2r[n];
      *(f32x4*)&edge_out[(size_t)eg * 64 + n*16 + g*4] = v;
      #pragma unroll
      for (int q = 0; q < 4; ++q)
        unsafeAtomicAdd(&agg[(size_t)dst * 64 + n*16 + g*4 + q], v[q]);
    }
  }
}

// Node model: x_out = relu([x|agg|f] @ Wn1 + bn1) @ Wn2 + bn2.
// agg aliases x_out (read row i, later overwrite row i within the owning wave).
__global__ __launch_bounds__(256, 1)
void node_kernel(const float* __restrict__ x, const float* agg,
                 const float* __restrict__ f,
                 const float* __restrict__ Wn1, const float* __restrict__ bn1,
                 const float* __restrict__ Wn2, const float* __restrict__ bn2,
                 float* x_out)
{
  __shared__ short sW1[128 * SW1];
  __shared__ short sW2[64 * SW2];
  __shared__ short sEin[64 * SEI];
  __shared__ short sEh[64 * SEH];

  const int t = threadIdx.x;
  const int lane = t & 63;
  const int w = t >> 6;
  const int r = lane & 15;
  const int g = lane >> 4;

  stage_weights(Wn1, Wn2, sW1, sW2, t);
  __syncthreads();

  s16x8 w1f[8][6];
  #pragma unroll
  for (int n = 0; n < 8; ++n) {
    #pragma unroll
    for (int kk = 0; kk < 6; ++kk)
      w1f[n][kk] = *(const s16x8*)&sW1[(n*16 + r) * SW1 + kk*32 + g*8];
  }
  s16x8 w2f[4][4];
  #pragma unroll
  for (int n = 0; n < 4; ++n) {
    #pragma unroll
    for (int kk = 0; kk < 4; ++kk)
      w2f[n][kk] = *(const s16x8*)&sW2[(n*16 + r) * SW2 + kk*32 + g*8];
  }
  f32x4 b1r[8], b2r[4];
  #pragma unroll
  for (int n = 0; n < 8; ++n) b1r[n] = *(const f32x4*)(bn1 + n*16 + g*4);
  #pragma unroll
  for (int n = 0; n < 4; ++n) b2r[n] = *(const f32x4*)(bn2 + n*16 + g*4);

  const int rl = t >> 2;
  const int p  = t & 3;
  short* stg = &sEin[rl*SEI + p*16];
  const short* erow = &sEin[(w*16 + r) * SEI + g*8];
  const short* hrow = &sEh[(w*16 + r) * SEH + g*8];

  const f32x4 zero = {0.f, 0.f, 0.f, 0.f};
  const int nTiles = (NN + 63) / 64;   // 313

  for (int tile = blockIdx.x; tile < nTiles; tile += (int)gridDim.x) {
    const int base = tile << 6;
    {
      const int i = base + rl;
      if (i < NN) {
        stage16(stg,       x   + (size_t)i*64 + p*16);
        stage16(stg + 64,  agg + (size_t)i*64 + p*16);
        stage16(stg + 128, f   + (size_t)i*64 + p*16);
      } else {
        s16x8 z = {0,0,0,0,0,0,0,0};
        ((s16x8*)stg)[0] = z;       ((s16x8*)stg)[1] = z;
        ((s16x8*)(stg+64))[0] = z;  ((s16x8*)(stg+64))[1] = z;
        ((s16x8*)(stg+128))[0] = z; ((s16x8*)(stg+128))[1] = z;
      }
    }

    f32x4 acc1[8];
    #pragma unroll
    for (int n = 0; n < 8; ++n) acc1[n] = zero;
    #pragma unroll
    for (int kk = 0; kk < 6; ++kk) {
      s16x8 ef = *(const s16x8*)(erow + kk*32);
      #pragma unroll
      for (int n = 0; n < 8; ++n)
        acc1[n] = __builtin_amdgcn_mfma_f32_16x16x32_bf16(w1f[n][kk], ef, acc1[n], 0, 0, 0);
    }
    #pragma unroll
    for (int n = 0; n < 8; ++n) {
      s16x4 pk;
      #pragma unroll
      for (int q = 0; q < 4; ++q) {
        float v = acc1[n][q] + b1r[n][q];
        pk[q] = f2bf(v > 0.f ? v : 0.f);
      }
      *(s16x4*)&sEh[(w*16 + r) * SEH + n*16 + g*4] = pk;
    }

    f32x4 acc2[4];
    #pragma unroll
    for (int n = 0; n < 4; ++n) acc2[n] = zero;
    #pragma unroll
    for (int kk = 0; kk < 4; ++kk) {
      s16x8 hf = *(const s16x8*)(hrow + kk*32);
      #pragma unroll
      for (int n = 0; n < 4; ++n)
        acc2[n] = __builtin_amdgcn_mfma_f32_16x16x32_bf16(w2f[n][kk], hf, acc2[n], 0, 0, 0);
    }
    const int rg = base + w*16 + r;
    if (rg < NN) {
      #pragma unroll
      for (int n = 0; n < 4; ++n) {
        f32x4 v = acc2[n] + b2r[n];
        *(f32x4*)&x_out[(size_t)rg * 64 + n*16 + g*4] = v;
      }
    }
  }
}

extern "C" void kernel_launch(void* const* d_in, const int* in_sizes, int n_in,
                              void* d_out, int out_size, void* d_ws, size_t ws_size,
                              hipStream_t stream) {
  const float* x   = (const float*)d_in[0];
  const int*   ei  = (const int*)d_in[1];
  const float* ea  = (const float*)d_in[2];
  const float* f   = (const float*)d_in[3];
  const float* We1 = (const float*)d_in[4];
  const float* be1 = (const float*)d_in[5];
  const float* We2 = (const float*)d_in[6];
  const float* be2 = (const float*)d_in[7];
  const float* Wn1 = (const float*)d_in[8];
  const float* bn1 = (const float*)d_in[9];
  const float* Wn2 = (const float*)d_in[10];
  const float* bn2 = (const float*)d_in[11];

  float* x_out    = (float*)d_out;                    // [20000*64] — doubles as agg
  float* edge_out = x_out + (size_t)NN * 64;          // [640000*64]

  // agg accumulator lives in the x_out slot: zero it, scatter-add, then node
  // kernel reads agg row i and overwrites it with x_out row i.
  hipMemsetAsync(x_out, 0, (size_t)NN * 64 * sizeof(float), stream);
  edge_kernel<<<256, 256, 0, stream>>>(x, ei, ea, We1, be1, We2, be2, edge_out, x_out);
  node_kernel<<<256, 256, 0, stream>>>(x, x_out, f, Wn1, bn1, Wn2, bn2, x_out);
}

// Round 2
// 374.443 us; speedup vs baseline: 1.5914x; 1.5914x over previous
//
#include <hip/hip_runtime.h>

#define NE 640000
#define NN 20000

typedef __attribute__((ext_vector_type(8))) short s16x8;
typedef __attribute__((ext_vector_type(4))) short s16x4;
typedef __attribute__((ext_vector_type(4))) float f32x4;

// LDS strides in bf16 elements (K padded +8 to spread banks)
#define SW1 200   // W1^T [128][192+8]
#define SW2 136   // W2^T [64][128+8]
#define SEI 200   // Ein  [64][192+8]
#define SEH 136   // Eh   [64][128+8]

__device__ __forceinline__ short f2bf(float f) {
  unsigned int u = __float_as_uint(f);
  u += 0x7fffu + ((u >> 16) & 1u);   // RNE
  return (short)(u >> 16);
}

// load 16 fp32, convert, store 32B to LDS (16B-aligned dst)
__device__ __forceinline__ void stage16(short* dst, const float* src) {
  const f32x4* s4 = (const f32x4*)src;
  f32x4 v0 = s4[0], v1 = s4[1], v2 = s4[2], v3 = s4[3];
  s16x8 lo, hi;
  lo[0]=f2bf(v0[0]); lo[1]=f2bf(v0[1]); lo[2]=f2bf(v0[2]); lo[3]=f2bf(v0[3]);
  lo[4]=f2bf(v1[0]); lo[5]=f2bf(v1[1]); lo[6]=f2bf(v1[2]); lo[7]=f2bf(v1[3]);
  hi[0]=f2bf(v2[0]); hi[1]=f2bf(v2[1]); hi[2]=f2bf(v2[2]); hi[3]=f2bf(v2[3]);
  hi[4]=f2bf(v3[0]); hi[5]=f2bf(v3[1]); hi[6]=f2bf(v3[2]); hi[7]=f2bf(v3[3]);
  ((s16x8*)dst)[0] = lo;
  ((s16x8*)dst)[1] = hi;
}

// W1 [192][128] -> sW1[h][k] (transposed, bf16); W2 [128][64] -> sW2[d][k]
__device__ __forceinline__ void stage_weights(const float* W1, const float* W2,
                                              short* sW1, short* sW2, int t) {
  #pragma unroll
  for (int i = 0; i < 24; ++i) {
    int idx4 = t + i * 256;                 // 6144 float4
    int k = idx4 >> 5;                      // row of W1 (k-dim)
    int n0 = (idx4 & 31) << 2;              // col (h-dim)
    f32x4 v = ((const f32x4*)W1)[idx4];
    sW1[(n0+0)*SW1 + k] = f2bf(v[0]);
    sW1[(n0+1)*SW1 + k] = f2bf(v[1]);
    sW1[(n0+2)*SW1 + k] = f2bf(v[2]);
    sW1[(n0+3)*SW1 + k] = f2bf(v[3]);
  }
  #pragma unroll
  for (int i = 0; i < 8; ++i) {
    int idx4 = t + i * 256;                 // 2048 float4
    int k = idx4 >> 4;
    int n0 = (idx4 & 15) << 2;
    f32x4 v = ((const f32x4*)W2)[idx4];
    sW2[(n0+0)*SW2 + k] = f2bf(v[0]);
    sW2[(n0+1)*SW2 + k] = f2bf(v[1]);
    sW2[(n0+2)*SW2 + k] = f2bf(v[2]);
    sW2[(n0+3)*SW2 + k] = f2bf(v[3]);
  }
}

// ---------------- CSR build ----------------

__global__ void count_kernel(const int* __restrict__ eidx, int* __restrict__ cursor) {
  for (int e = blockIdx.x * blockDim.x + threadIdx.x; e < NE;
       e += gridDim.x * blockDim.x)
    atomicAdd(&cursor[eidx[NE + e]], 1);
}

// single block: exclusive scan of counts -> offs[0..NN] and cursor (scatter base)
__global__ __launch_bounds__(256)
void scan_kernel(int* __restrict__ cursor, int* __restrict__ offs) {
  __shared__ int part[256];
  const int t = threadIdx.x;
  const int CH = (NN + 255) / 256;          // 79
  const int lo = t * CH, hi = min(lo + CH, NN);
  int s = 0;
  for (int i = lo; i < hi; ++i) s += cursor[i];
  part[t] = s;
  __syncthreads();
  // inclusive Hillis-Steele over 256 partials
  for (int d = 1; d < 256; d <<= 1) {
    int u = (t >= d) ? part[t - d] : 0;
    __syncthreads();
    part[t] += u;
    __syncthreads();
  }
  int run = part[t] - s;                    // exclusive base
  for (int i = lo; i < hi; ++i) {
    int c = cursor[i];
    offs[i] = run;
    cursor[i] = run;
    run += c;
  }
  if (t == 255) offs[NN] = run;             // == NE
}

__global__ void scatter_kernel(const int* __restrict__ eidx,
                               int* __restrict__ cursor, int* __restrict__ elist) {
  for (int e = blockIdx.x * blockDim.x + threadIdx.x; e < NE;
       e += gridDim.x * blockDim.x) {
    int pos = atomicAdd(&cursor[eidx[NE + e]], 1);
    elist[pos] = e;
  }
}

// ---------------- edge model ----------------
// e_h = relu([x_s|x_d|ea] @ W1 + b1), out = e_h @ W2 + b2, computed transposed
// (D' = W^T * Ein^T) so weights are the A-operand and live in registers; each
// wave owns 16 edges (its own LDS rows) -> no in-loop barriers.
__global__ __launch_bounds__(256, 1)
void edge_kernel(const float* __restrict__ x, const int* __restrict__ eidx,
                 const float* __restrict__ ea,
                 const float* __restrict__ We1, const float* __restrict__ be1,
                 const float* __restrict__ We2, const float* __restrict__ be2,
                 float* __restrict__ edge_out)
{
  __shared__ short sW1[128 * SW1];
  __shared__ short sW2[64 * SW2];
  __shared__ short sEin[64 * SEI];
  __shared__ short sEh[64 * SEH];

  const int t = threadIdx.x;
  const int lane = t & 63;
  const int w = t >> 6;          // wave 0..3
  const int r = lane & 15;
  const int g = lane >> 4;

  stage_weights(We1, We2, sW1, sW2, t);
  __syncthreads();

  // weight fragments in registers: A-operand = W^T tile rows (h / d dims)
  s16x8 w1f[8][6];
  #pragma unroll
  for (int n = 0; n < 8; ++n) {
    #pragma unroll
    for (int kk = 0; kk < 6; ++kk)
      w1f[n][kk] = *(const s16x8*)&sW1[(n*16 + r) * SW1 + kk*32 + g*8];
  }
  s16x8 w2f[4][4];
  #pragma unroll
  for (int n = 0; n < 4; ++n) {
    #pragma unroll
    for (int kk = 0; kk < 4; ++kk)
      w2f[n][kk] = *(const s16x8*)&sW2[(n*16 + r) * SW2 + kk*32 + g*8];
  }
  f32x4 b1r[8], b2r[4];
  #pragma unroll
  for (int n = 0; n < 8; ++n) b1r[n] = *(const f32x4*)(be1 + n*16 + g*4);
  #pragma unroll
  for (int n = 0; n < 4; ++n) b2r[n] = *(const f32x4*)(be2 + n*16 + g*4);

  // per-thread constant LDS addresses
  const int el = t >> 2;         // edge slot 0..63 (wave-private range)
  const int p  = t & 3;          // 16-col chunk
  short* stg = &sEin[el*SEI + p*16];
  const short* erow = &sEin[(w*16 + r) * SEI + g*8];
  const short* hrow = &sEh[(w*16 + r) * SEH + g*8];

  const f32x4 zero = {0.f, 0.f, 0.f, 0.f};

  for (int tile = blockIdx.x; tile < NE/64; tile += (int)gridDim.x) {
    const int ebase = tile << 6;
    {
      const int e = ebase + el;
      const int s = eidx[e];
      const int d = eidx[NE + e];
      stage16(stg,       x  + (size_t)s*64 + p*16);
      stage16(stg + 64,  x  + (size_t)d*64 + p*16);
      stage16(stg + 128, ea + (size_t)e*64 + p*16);
    }

    // layer 1: acc1[h-tile] = W1^T * Ein^T   (lane: col=edge r, rows=h g*4+q)
    f32x4 acc1[8];
    #pragma unroll
    for (int n = 0; n < 8; ++n) acc1[n] = zero;
    #pragma unroll
    for (int kk = 0; kk < 6; ++kk) {
      s16x8 ef = *(const s16x8*)(erow + kk*32);
      #pragma unroll
      for (int n = 0; n < 8; ++n)
        acc1[n] = __builtin_amdgcn_mfma_f32_16x16x32_bf16(w1f[n][kk], ef, acc1[n], 0, 0, 0);
    }
    // bias + relu + packed bf16 row write (4 contiguous h per lane)
    #pragma unroll
    for (int n = 0; n < 8; ++n) {
      s16x4 pk;
      #pragma unroll
      for (int q = 0; q < 4; ++q) {
        float v = acc1[n][q] + b1r[n][q];
        pk[q] = f2bf(v > 0.f ? v : 0.f);
      }
      *(s16x4*)&sEh[(w*16 + r) * SEH + n*16 + g*4] = pk;
    }

    // layer 2: acc2[d-tile] = W2^T * Eh^T
    f32x4 acc2[4];
    #pragma unroll
    for (int n = 0; n < 4; ++n) acc2[n] = zero;
    #pragma unroll
    for (int kk = 0; kk < 4; ++kk) {
      s16x8 hf = *(const s16x8*)(hrow + kk*32);
      #pragma unroll
      for (int n = 0; n < 4; ++n)
        acc2[n] = __builtin_amdgcn_mfma_f32_16x16x32_bf16(w2f[n][kk], hf, acc2[n], 0, 0, 0);
    }
    const int eg = ebase + w*16 + r;
    #pragma unroll
    for (int n = 0; n < 4; ++n) {
      f32x4 v = acc2[n] + b2r[n];
      *(f32x4*)&edge_out[(size_t)eg * 64 + n*16 + g*4] = v;
    }
  }
}

// ---------------- aggregation (gather) ----------------
// one wave per node; lane = feature column; fully coalesced 256B read per edge
__global__ __launch_bounds__(256)
void agg_kernel(const float* __restrict__ eo, const int* __restrict__ offs,
                const int* __restrict__ elist, float* __restrict__ agg) {
  const int w = threadIdx.x >> 6;
  const int lane = threadIdx.x & 63;
  for (int i = blockIdx.x * 4 + w; i < NN; i += (int)gridDim.x * 4) {
    int j = offs[i];
    const int end = offs[i + 1];
    float acc = 0.f;
    for (; j + 4 <= end; j += 4) {
      int e0 = elist[j], e1 = elist[j+1], e2 = elist[j+2], e3 = elist[j+3];
      float v0 = eo[(size_t)e0*64 + lane];
      float v1 = eo[(size_t)e1*64 + lane];
      float v2 = eo[(size_t)e2*64 + lane];
      float v3 = eo[(size_t)e3*64 + lane];
      acc += (v0 + v1) + (v2 + v3);
    }
    for (; j < end; ++j) acc += eo[(size_t)elist[j]*64 + lane];
    agg[(size_t)i*64 + lane] = acc;
  }
}

// ---------------- node model ----------------
// x_out = relu([x|agg|f] @ Wn1 + bn1) @ Wn2 + bn2.
// agg aliases x_out (read row i, later overwrite row i within the owning wave).
__global__ __launch_bounds__(256, 1)
void node_kernel(const float* __restrict__ x, const float* agg,
                 const float* __restrict__ f,
                 const float* __restrict__ Wn1, const float* __restrict__ bn1,
                 const float* __restrict__ Wn2, const float* __restrict__ bn2,
                 float* x_out)
{
  __shared__ short sW1[128 * SW1];
  __shared__ short sW2[64 * SW2];
  __shared__ short sEin[64 * SEI];
  __shared__ short sEh[64 * SEH];

  const int t = threadIdx.x;
  const int lane = t & 63;
  const int w = t >> 6;
  const int r = lane & 15;
  const int g = lane >> 4;

  stage_weights(Wn1, Wn2, sW1, sW2, t);
  __syncthreads();

  s16x8 w1f[8][6];
  #pragma unroll
  for (int n = 0; n < 8; ++n) {
    #pragma unroll
    for (int kk = 0; kk < 6; ++kk)
      w1f[n][kk] = *(const s16x8*)&sW1[(n*16 + r) * SW1 + kk*32 + g*8];
  }
  s16x8 w2f[4][4];
  #pragma unroll
  for (int n = 0; n < 4; ++n) {
    #pragma unroll
    for (int kk = 0; kk < 4; ++kk)
      w2f[n][kk] = *(const s16x8*)&sW2[(n*16 + r) * SW2 + kk*32 + g*8];
  }
  f32x4 b1r[8], b2r[4];
  #pragma unroll
  for (int n = 0; n < 8; ++n) b1r[n] = *(const f32x4*)(bn1 + n*16 + g*4);
  #pragma unroll
  for (int n = 0; n < 4; ++n) b2r[n] = *(const f32x4*)(bn2 + n*16 + g*4);

  const int rl = t >> 2;
  const int p  = t & 3;
  short* stg = &sEin[rl*SEI + p*16];
  const short* erow = &sEin[(w*16 + r) * SEI + g*8];
  const short* hrow = &sEh[(w*16 + r) * SEH + g*8];

  const f32x4 zero = {0.f, 0.f, 0.f, 0.f};
  const int nTiles = (NN + 63) / 64;   // 313

  for (int tile = blockIdx.x; tile < nTiles; tile += (int)gridDim.x) {
    const int base = tile << 6;
    {
      const int i = base + rl;
      if (i < NN) {
        stage16(stg,       x   + (size_t)i*64 + p*16);
        stage16(stg + 64,  agg + (size_t)i*64 + p*16);
        stage16(stg + 128, f   + (size_t)i*64 + p*16);
      } else {
        s16x8 z = {0,0,0,0,0,0,0,0};
        ((s16x8*)stg)[0] = z;       ((s16x8*)stg)[1] = z;
        ((s16x8*)(stg+64))[0] = z;  ((s16x8*)(stg+64))[1] = z;
        ((s16x8*)(stg+128))[0] = z; ((s16x8*)(stg+128))[1] = z;
      }
    }

    f32x4 acc1[8];
    #pragma unroll
    for (int n = 0; n < 8; ++n) acc1[n] = zero;
    #pragma unroll
    for (int kk = 0; kk < 6; ++kk) {
      s16x8 ef = *(const s16x8*)(erow + kk*32);
      #pragma unroll
      for (int n = 0; n < 8; ++n)
        acc1[n] = __builtin_amdgcn_mfma_f32_16x16x32_bf16(w1f[n][kk], ef, acc1[n], 0, 0, 0);
    }
    #pragma unroll
    for (int n = 0; n < 8; ++n) {
      s16x4 pk;
      #pragma unroll
      for (int q = 0; q < 4; ++q) {
        float v = acc1[n][q] + b1r[n][q];
        pk[q] = f2bf(v > 0.f ? v : 0.f);
      }
      *(s16x4*)&sEh[(w*16 + r) * SEH + n*16 + g*4] = pk;
    }

    f32x4 acc2[4];
    #pragma unroll
    for (int n = 0; n < 4; ++n) acc2[n] = zero;
    #pragma unroll
    for (int kk = 0; kk < 4; ++kk) {
      s16x8 hf = *(const s16x8*)(hrow + kk*32);
      #pragma unroll
      for (int n = 0; n < 4; ++n)
        acc2[n] = __builtin_amdgcn_mfma_f32_16x16x32_bf16(w2f[n][kk], hf, acc2[n], 0, 0, 0);
    }
    const int rg = base + w*16 + r;
    if (rg < NN) {
      #pragma unroll
      for (int n = 0; n < 4; ++n) {
        f32x4 v = acc2[n] + b2r[n];
        *(f32x4*)&x_out[(size_t)rg * 64 + n*16 + g*4] = v;
      }
    }
  }
}

extern "C" void kernel_launch(void* const* d_in, const int* in_sizes, int n_in,
                              void* d_out, int out_size, void* d_ws, size_t ws_size,
                              hipStream_t stream) {
  const float* x   = (const float*)d_in[0];
  const int*   ei  = (const int*)d_in[1];
  const float* ea  = (const float*)d_in[2];
  const float* f   = (const float*)d_in[3];
  const float* We1 = (const float*)d_in[4];
  const float* be1 = (const float*)d_in[5];
  const float* We2 = (const float*)d_in[6];
  const float* be2 = (const float*)d_in[7];
  const float* Wn1 = (const float*)d_in[8];
  const float* bn1 = (const float*)d_in[9];
  const float* Wn2 = (const float*)d_in[10];
  const float* bn2 = (const float*)d_in[11];

  float* x_out    = (float*)d_out;                    // [20000*64] — doubles as agg
  float* edge_out = x_out + (size_t)NN * 64;          // [640000*64]

  // CSR scratch in d_ws: cursor[NN] | offs[NN+1] | elist[NE]  (~2.8 MB)
  int* cursor = (int*)d_ws;
  int* offs   = cursor + NN;
  int* elist  = offs + NN + 8;                        // keep 16B alignment slack

  hipMemsetAsync(cursor, 0, NN * sizeof(int), stream);
  count_kernel<<<512, 256, 0, stream>>>(ei, cursor);
  scan_kernel<<<1, 256, 0, stream>>>(cursor, offs);
  scatter_kernel<<<512, 256, 0, stream>>>(ei, cursor, elist);
  edge_kernel<<<256, 256, 0, stream>>>(x, ei, ea, We1, be1, We2, be2, edge_out);
  agg_kernel<<<1024, 256, 0, stream>>>(edge_out, offs, elist, x_out);
  node_kernel<<<256, 256, 0, stream>>>(x, x_out, f, Wn1, bn1, Wn2, bn2, x_out);
}